// Round 14
// baseline (267.864 us; speedup 1.0000x reference)
//
#include <hip/hip_runtime.h>
#include <stdint.h>

// 3-layer GCN, gather-only aggregation off a per-node CSR.
// R13 = R12 (243.7us) + (1) non-temporal loads for all stream-once arrays
// (edge list, binned, csr, iptr2, aggh) so they stop evicting the L2-resident
// gather targets (p1/p2/p3); (2) x4 mid-stage remainder in the gather loops
// (serial tail <=3 instead of <=7 loads; deg~Poisson(16)).
// Packed edge = (src<<9)|(dst&511), src < 2^18. Aggregation accumulators
// FP64 (order-independent accuracy; CSR order nondeterministic). dim-30
// intermediates bf16 64B rows; k_agg30 = 8-lane groups x uint2.

#define CAP 9216    // bucket region capacity; mean 8184, sigma 90 -> +11 sigma
#define CHUNK 6400  // edges per k_bin block (500 blocks ~= 2/CU exactly)

__device__ __forceinline__ unsigned short f2bf(float f) {  // RNE, no NaN inputs
    unsigned u = __float_as_uint(f);
    unsigned r = ((u >> 16) & 1u) + 0x7FFFu;
    return (unsigned short)((u + r) >> 16);
}
__device__ __forceinline__ float bf2f(unsigned short h) {
    return __uint_as_float((unsigned)h << 16);
}
__device__ __forceinline__ int ntl(const int* p) { return __builtin_nontemporal_load(p); }
__device__ __forceinline__ unsigned ntlu(const unsigned* p) { return __builtin_nontemporal_load(p); }
__device__ __forceinline__ long long ntll(const long long* p) { return __builtin_nontemporal_load(p); }
__device__ __forceinline__ int2 ntl2(const int2* p) {
    const int* q = (const int*)p;
    return make_int2(__builtin_nontemporal_load(q), __builtin_nontemporal_load(q + 1));
}

// Per-block int64-vs-int32 detect: int64 edge values < 2^18 => all high
// words zero; int32 data at those offsets is src values, ~surely nonzero.
__device__ __forceinline__ int detect64(const unsigned* ei, int* s_nz, int t) {
    unsigned v = ei[2 * (t & 255) + 1];
    if (v != 0) atomicAdd(s_nz, 1);
    __syncthreads();
    return (*s_nz == 0);
}

// Fused binning with local counting sort and coalesced copy-out. 512 thr.
__global__ __launch_bounds__(512) void k_bin(const void* ei, long long E,
                                             int* gcnt, unsigned* binned, int B) {
    __shared__ int cursor[512];
    __shared__ int delta[512];
    __shared__ int wsum[8];
    __shared__ int s_total;
    __shared__ unsigned sv[CHUNK];
    __shared__ unsigned short sb[CHUNK];
    __shared__ int s_nz;
    int t = threadIdx.x, blk = blockIdx.x;
    if (t == 0) s_nz = 0;
    cursor[t] = 0;
    __syncthreads();
    int f = detect64((const unsigned*)ei, &s_nz, t);
    long long s = (long long)blk * CHUNK, e = min(E, s + CHUNK);
    if (f) {
        const long long* p = (const long long*)ei;
        for (long long i = s + t; i < e; i += 512)
            atomicAdd(&cursor[((int)ntll(p + E + i)) >> 9], 1);
    } else {
        const int* p = (const int*)ei;
        for (long long i = s + t; i < e; i += 512)
            atomicAdd(&cursor[ntl(p + E + i) >> 9], 1);
    }
    __syncthreads();
    // exclusive scan over 512 counts: wave shuffle scan + cross-wave offsets
    int c = cursor[t];
    int lane = t & 63, wid = t >> 6;
    int inc = c;
#pragma unroll
    for (int off = 1; off < 64; off <<= 1) {
        int up = __shfl_up(inc, off, 64);
        if (lane >= off) inc += up;
    }
    if (lane == 63) wsum[wid] = inc;
    __syncthreads();
    int base = 0;
    for (int k = 0; k < wid; k++) base += wsum[k];
    int ex = base + inc - c;
    if (t == 511) s_total = ex + c;
    int claim = c ? atomicAdd(&gcnt[t], c) : 0;
    delta[t] = t * CAP + claim - ex;
    cursor[t] = ex;
    __syncthreads();
    // scatter into LDS (sorted by bucket), remember bucket id
    if (f) {
        const long long* p = (const long long*)ei;
        for (long long i = s + t; i < e; i += 512) {
            int sval = (int)ntll(p + i), dv = (int)ntll(p + E + i);
            int b = dv >> 9;
            int pos = atomicAdd(&cursor[b], 1);
            sv[pos] = ((unsigned)sval << 9) | (unsigned)(dv & 511);
            sb[pos] = (unsigned short)b;
        }
    } else {
        const int* p = (const int*)ei;
        for (long long i = s + t; i < e; i += 512) {
            int sval = ntl(p + i), dv = ntl(p + E + i);
            int b = dv >> 9;
            int pos = atomicAdd(&cursor[b], 1);
            sv[pos] = ((unsigned)sval << 9) | (unsigned)(dv & 511);
            sb[pos] = (unsigned short)b;
        }
    }
    __syncthreads();
    // linear copy-out (consecutive threads -> consecutive addresses)
    int total = s_total;
    for (int i = t; i < total; i += 512)
        binned[delta[sb[i]] + i] = sv[i];
}

// Per-bucket counting sort by local node, scattering csr DIRECTLY to the
// block-owned global region. 1024 threads; shuffle scan over 512 counters.
// Also iptr2, dinv, p1 = x*dinv.
__global__ __launch_bounds__(1024) void k_bucket_csr(
        const unsigned* binned, const int* gcnt, const float* x, int2* iptr2,
        float* dinv, float2* p1, int* csr, int n) {
    __shared__ int cur[512];
    __shared__ int wsum[16];
    int t = threadIdx.x, b = blockIdx.x;
    if (t < 512) cur[t] = 0;
    __syncthreads();
    int cnt = gcnt[b];
    const unsigned* bp = binned + (size_t)b * CAP;
    for (int i = t; i < cnt; i += 1024)
        atomicAdd(&cur[ntlu(bp + i) & 511u], 1);
    __syncthreads();
    int c = (t < 512) ? cur[t] : 0;
    int lane = t & 63, wid = t >> 6;
    int inc = c;
#pragma unroll
    for (int off = 1; off < 64; off <<= 1) {
        int up = __shfl_up(inc, off, 64);
        if (lane >= off) inc += up;
    }
    if (lane == 63) wsum[wid] = inc;
    __syncthreads();
    int base = 0;
    for (int k = 0; k < wid; k++) base += wsum[k];
    int ex = base + inc - c;
    int gbase = b * CAP;
    if (t < 512) {
        cur[t] = gbase + ex;  // global cursor
        int node = b * 512 + t;
        if (node < n) {
            iptr2[node] = make_int2(gbase + ex, gbase + ex + c);
            float dg = (float)(c + 1);  // +1 self loop
            float r = rsqrtf(dg);
            r = r * (1.5f - 0.5f * dg * r * r);  // Newton refine
            dinv[node] = r;
            p1[node] = make_float2(x[2 * node] * r, x[2 * node + 1] * r);
        }
    }
    __syncthreads();
    for (int i = t; i < cnt; i += 1024) {
        unsigned p = ntlu(bp + i);
        int pos = atomicAdd(&cur[p & 511u], 1);
        csr[pos] = (int)(p >> 9);
    }
}

// Fused: aggx = A_hat x (dim2, x8+x4 unroll, fp64 acc);
// p2 = bf16(relu(aggx@W1+b1)*dinv), 64B rows (32 ushorts, 2 zero pads).
__global__ void k_agg2_l1(const float2* p1, const int2* iptr2, const int* csr,
                          const float* dinv, const float* W1, const float* b1,
                          float2* aggx, unsigned short* p2, int n) {
    int v = blockIdx.x * 256 + threadIdx.x;
    if (v >= n) return;
    float2 a0 = p1[v];
    double dax = a0.x, day = a0.y;
    int2 se = ntl2(iptr2 + v);
    int s = se.x, e = se.y;
    int i = s;
    for (; i + 7 < e; i += 8) {
        int u0 = ntl(csr + i), u1 = ntl(csr + i + 1), u2 = ntl(csr + i + 2), u3 = ntl(csr + i + 3);
        int u4 = ntl(csr + i + 4), u5 = ntl(csr + i + 5), u6 = ntl(csr + i + 6), u7 = ntl(csr + i + 7);
        float2 q0 = p1[u0], q1 = p1[u1], q2 = p1[u2], q3 = p1[u3];
        float2 q4 = p1[u4], q5 = p1[u5], q6 = p1[u6], q7 = p1[u7];
        dax += ((double)q0.x + q1.x) + ((double)q2.x + q3.x) +
               ((double)q4.x + q5.x) + ((double)q6.x + q7.x);
        day += ((double)q0.y + q1.y) + ((double)q2.y + q3.y) +
               ((double)q4.y + q5.y) + ((double)q6.y + q7.y);
    }
    if (i + 3 < e) {
        int u0 = ntl(csr + i), u1 = ntl(csr + i + 1), u2 = ntl(csr + i + 2), u3 = ntl(csr + i + 3);
        float2 q0 = p1[u0], q1 = p1[u1], q2 = p1[u2], q3 = p1[u3];
        dax += ((double)q0.x + q1.x) + ((double)q2.x + q3.x);
        day += ((double)q0.y + q1.y) + ((double)q2.y + q3.y);
        i += 4;
    }
    for (; i < e; i++) {
        float2 q = p1[ntl(csr + i)];
        dax += (double)q.x; day += (double)q.y;
    }
    float r = dinv[v];
    float ax = (float)(dax * (double)r), ay = (float)(day * (double)r);
    aggx[v] = make_float2(ax, ay);
    __align__(16) unsigned short ob[32];
#pragma unroll
    for (int j = 0; j < 30; j++)
        ob[j] = f2bf(fmaxf(fmaf(ax, W1[j], fmaf(ay, W1[30 + j], b1[j])), 0.f) * r);
    ob[30] = 0; ob[31] = 0;
    uint4* d4 = (uint4*)(p2 + (size_t)v * 32);
    const uint4* s4 = (const uint4*)ob;
#pragma unroll
    for (int k = 0; k < 4; k++) d4[k] = s4[k];
}

// Dim-30 aggregation: 8-lane group per node, each lane a uint2 (4 bf16,
// 64B/row/group), x8+x4 unrolled independent gathers, fp64 accumulators.
__global__ void k_agg30(const uint2* p2u, const int2* iptr2,
                        const int* csr, const float* dinv,
                        uint2* agghu, int n) {
    int t = threadIdx.x;
    int g = blockIdx.x * 32 + (t >> 3);
    int l = t & 7;
    if (g >= n) return;
    uint2 w = p2u[(size_t)g * 8 + l];  // self loop (pads zero)
    double a0 = (double)bf2f((unsigned short)(w.x & 0xFFFFu));
    double a1 = (double)bf2f((unsigned short)(w.x >> 16));
    double a2 = (double)bf2f((unsigned short)(w.y & 0xFFFFu));
    double a3 = (double)bf2f((unsigned short)(w.y >> 16));
    int2 se = ntl2(iptr2 + g);
    int s = se.x, e = se.y;
    int i = s;
    for (; i + 7 < e; i += 8) {
        int u0 = ntl(csr + i), u1 = ntl(csr + i + 1), u2 = ntl(csr + i + 2), u3 = ntl(csr + i + 3);
        int u4 = ntl(csr + i + 4), u5 = ntl(csr + i + 5), u6 = ntl(csr + i + 6), u7 = ntl(csr + i + 7);
        uint2 w0 = p2u[(size_t)u0 * 8 + l];
        uint2 w1 = p2u[(size_t)u1 * 8 + l];
        uint2 w2 = p2u[(size_t)u2 * 8 + l];
        uint2 w3 = p2u[(size_t)u3 * 8 + l];
        uint2 w4 = p2u[(size_t)u4 * 8 + l];
        uint2 w5 = p2u[(size_t)u5 * 8 + l];
        uint2 w6 = p2u[(size_t)u6 * 8 + l];
        uint2 w7 = p2u[(size_t)u7 * 8 + l];
        a0 += ((double)bf2f((unsigned short)(w0.x & 0xFFFFu)) + bf2f((unsigned short)(w1.x & 0xFFFFu))) +
              ((double)bf2f((unsigned short)(w2.x & 0xFFFFu)) + bf2f((unsigned short)(w3.x & 0xFFFFu))) +
              ((double)bf2f((unsigned short)(w4.x & 0xFFFFu)) + bf2f((unsigned short)(w5.x & 0xFFFFu))) +
              ((double)bf2f((unsigned short)(w6.x & 0xFFFFu)) + bf2f((unsigned short)(w7.x & 0xFFFFu)));
        a1 += ((double)bf2f((unsigned short)(w0.x >> 16)) + bf2f((unsigned short)(w1.x >> 16))) +
              ((double)bf2f((unsigned short)(w2.x >> 16)) + bf2f((unsigned short)(w3.x >> 16))) +
              ((double)bf2f((unsigned short)(w4.x >> 16)) + bf2f((unsigned short)(w5.x >> 16))) +
              ((double)bf2f((unsigned short)(w6.x >> 16)) + bf2f((unsigned short)(w7.x >> 16)));
        a2 += ((double)bf2f((unsigned short)(w0.y & 0xFFFFu)) + bf2f((unsigned short)(w1.y & 0xFFFFu))) +
              ((double)bf2f((unsigned short)(w2.y & 0xFFFFu)) + bf2f((unsigned short)(w3.y & 0xFFFFu))) +
              ((double)bf2f((unsigned short)(w4.y & 0xFFFFu)) + bf2f((unsigned short)(w5.y & 0xFFFFu))) +
              ((double)bf2f((unsigned short)(w6.y & 0xFFFFu)) + bf2f((unsigned short)(w7.y & 0xFFFFu)));
        a3 += ((double)bf2f((unsigned short)(w0.y >> 16)) + bf2f((unsigned short)(w1.y >> 16))) +
              ((double)bf2f((unsigned short)(w2.y >> 16)) + bf2f((unsigned short)(w3.y >> 16))) +
              ((double)bf2f((unsigned short)(w4.y >> 16)) + bf2f((unsigned short)(w5.y >> 16))) +
              ((double)bf2f((unsigned short)(w6.y >> 16)) + bf2f((unsigned short)(w7.y >> 16)));
    }
    if (i + 3 < e) {
        int u0 = ntl(csr + i), u1 = ntl(csr + i + 1), u2 = ntl(csr + i + 2), u3 = ntl(csr + i + 3);
        uint2 w0 = p2u[(size_t)u0 * 8 + l];
        uint2 w1 = p2u[(size_t)u1 * 8 + l];
        uint2 w2 = p2u[(size_t)u2 * 8 + l];
        uint2 w3 = p2u[(size_t)u3 * 8 + l];
        a0 += ((double)bf2f((unsigned short)(w0.x & 0xFFFFu)) + bf2f((unsigned short)(w1.x & 0xFFFFu))) +
              ((double)bf2f((unsigned short)(w2.x & 0xFFFFu)) + bf2f((unsigned short)(w3.x & 0xFFFFu)));
        a1 += ((double)bf2f((unsigned short)(w0.x >> 16)) + bf2f((unsigned short)(w1.x >> 16))) +
              ((double)bf2f((unsigned short)(w2.x >> 16)) + bf2f((unsigned short)(w3.x >> 16)));
        a2 += ((double)bf2f((unsigned short)(w0.y & 0xFFFFu)) + bf2f((unsigned short)(w1.y & 0xFFFFu))) +
              ((double)bf2f((unsigned short)(w2.y & 0xFFFFu)) + bf2f((unsigned short)(w3.y & 0xFFFFu)));
        a3 += ((double)bf2f((unsigned short)(w0.y >> 16)) + bf2f((unsigned short)(w1.y >> 16))) +
              ((double)bf2f((unsigned short)(w2.y >> 16)) + bf2f((unsigned short)(w3.y >> 16)));
        i += 4;
    }
    for (; i < e; i++) {
        uint2 wv = p2u[(size_t)ntl(csr + i) * 8 + l];
        a0 += (double)bf2f((unsigned short)(wv.x & 0xFFFFu));
        a1 += (double)bf2f((unsigned short)(wv.x >> 16));
        a2 += (double)bf2f((unsigned short)(wv.y & 0xFFFFu));
        a3 += (double)bf2f((unsigned short)(wv.y >> 16));
    }
    double r = (double)dinv[g];
    uint2 o;
    o.x = (unsigned)f2bf((float)(a0 * r)) | ((unsigned)f2bf((float)(a1 * r)) << 16);
    o.y = (unsigned)f2bf((float)(a2 * r)) | ((unsigned)f2bf((float)(a3 * r)) << 16);
    agghu[(size_t)g * 8 + l] = o;  // pads (cols 30,31) are zero-sums -> stay 0
}

// h2 = relu((Ah1)W2[:30] + (Ax)W2[30:] + b2); p3 = ([h2,x]@W3) * dinv.
// Block stages its 256 bf16 aggh rows through LDS (stride-17 uints).
__global__ void k_layer2(const unsigned short* aggh, const float2* aggx,
                         const float* x, const float* W2, const float* W3,
                         const float* b2, const float* dinv, float* p3, int n) {
    __shared__ float W2s[32 * 30];
    __shared__ float W3s[32];
    __shared__ float b2s[30];
    __shared__ unsigned hsh[256 * 17];
    int t = threadIdx.x;
    for (int i = t; i < 960; i += 256) W2s[i] = W2[i];
    if (t < 32) W3s[t] = W3[t];
    if (t < 30) b2s[t] = b2[t];
    const unsigned* ag = (const unsigned*)aggh + (size_t)blockIdx.x * 256 * 16;
    int rows = min(256, n - blockIdx.x * 256);
    for (int i = t; i < rows * 16; i += 256) {
        int rr = i >> 4, cc = i & 15;
        hsh[rr * 17 + cc] = ntlu(ag + i);
    }
    __syncthreads();
    int v = blockIdx.x * 256 + t;
    if (v >= n) return;
    float2 a = aggx[v];
    float acc[30];
#pragma unroll
    for (int j = 0; j < 30; j++)
        acc[j] = fmaf(a.x, W2s[30 * 30 + j], fmaf(a.y, W2s[31 * 30 + j], b2s[j]));
#pragma unroll
    for (int kk = 0; kk < 15; kk++) {  // 30 values = 15 uint pairs
        unsigned pr = hsh[t * 17 + kk];
        float h0 = bf2f((unsigned short)(pr & 0xFFFFu));
        float h1v = bf2f((unsigned short)(pr >> 16));
#pragma unroll
        for (int j = 0; j < 30; j++)
            acc[j] = fmaf(h0, W2s[(2 * kk) * 30 + j], acc[j]);
#pragma unroll
        for (int j = 0; j < 30; j++)
            acc[j] = fmaf(h1v, W2s[(2 * kk + 1) * 30 + j], acc[j]);
    }
    float s3 = 0.f;
#pragma unroll
    for (int j = 0; j < 30; j++) s3 = fmaf(fmaxf(acc[j], 0.f), W3s[j], s3);
    s3 = fmaf(x[2 * v], W3s[30], s3);
    s3 = fmaf(x[2 * v + 1], W3s[31], s3);
    p3[v] = s3 * dinv[v];
}

// out_v = dinv_v * (p3_v + sum p3_u) + b3   (dim 1, x8+x4 unroll, fp64 acc)
__global__ void k_agg1(const float* p3, const int2* iptr2, const int* csr,
                       const float* dinv, const float* b3, float* out, int n) {
    int v = blockIdx.x * 256 + threadIdx.x;
    if (v >= n) return;
    double acc = (double)p3[v];
    int2 se = ntl2(iptr2 + v);
    int s = se.x, e = se.y;
    int i = s;
    for (; i + 7 < e; i += 8) {
        int u0 = ntl(csr + i), u1 = ntl(csr + i + 1), u2 = ntl(csr + i + 2), u3 = ntl(csr + i + 3);
        int u4 = ntl(csr + i + 4), u5 = ntl(csr + i + 5), u6 = ntl(csr + i + 6), u7 = ntl(csr + i + 7);
        float f0 = p3[u0], f1 = p3[u1], f2 = p3[u2], f3 = p3[u3];
        float f4 = p3[u4], f5 = p3[u5], f6 = p3[u6], f7 = p3[u7];
        acc += ((double)f0 + f1) + ((double)f2 + f3) +
               ((double)f4 + f5) + ((double)f6 + f7);
    }
    if (i + 3 < e) {
        int u0 = ntl(csr + i), u1 = ntl(csr + i + 1), u2 = ntl(csr + i + 2), u3 = ntl(csr + i + 3);
        float f0 = p3[u0], f1 = p3[u1], f2 = p3[u2], f3 = p3[u3];
        acc += ((double)f0 + f1) + ((double)f2 + f3);
        i += 4;
    }
    for (; i < e; i++) acc += (double)p3[ntl(csr + i)];
    out[v] = (float)(acc * (double)dinv[v] + (double)b3[0]);
}

extern "C" void kernel_launch(void* const* d_in, const int* in_sizes, int n_in,
                              void* d_out, int out_size, void* d_ws, size_t ws_size,
                              hipStream_t stream) {
    const float* x  = (const float*)d_in[0];
    const void*  ei = d_in[1];
    const float* W1 = (const float*)d_in[2];
    const float* b1 = (const float*)d_in[3];
    const float* W2 = (const float*)d_in[4];
    const float* b2 = (const float*)d_in[5];
    const float* W3 = (const float*)d_in[6];
    const float* b3 = (const float*)d_in[7];
    float* out = (float*)d_out;
    const int n = in_sizes[0] / 2;
    const long long E = in_sizes[1] / 2;
    const int B = (n + 511) / 512;  // dst buckets of 512 nodes (<=512 buckets)

    char* w = (char*)d_ws;
    auto alloc = [&](size_t b) { void* p = (void*)w; w += (b + 255) & ~(size_t)255; return p; };
    int*            gcnt   = (int*)alloc(512 * 4);
    unsigned*       binned = (unsigned*)alloc((size_t)B * CAP * 4);
    int*            csr    = (int*)alloc((size_t)B * CAP * 4);
    int2*           iptr2  = (int2*)alloc((size_t)n * 8);
    float*          dinv   = (float*)alloc((size_t)n * 4);
    float2*         p1     = (float2*)alloc((size_t)n * 8);
    float2*         aggx   = (float2*)alloc((size_t)n * 8);
    unsigned short* p2     = (unsigned short*)alloc((size_t)n * 32 * 2);
    unsigned short* aggh   = (unsigned short*)alloc((size_t)n * 32 * 2);
    float*          p3     = (float*)alloc((size_t)n * 4);

    int nblocks = (n + 255) / 256;
    int nbin = (int)((E + CHUNK - 1) / CHUNK);

    hipMemsetAsync(gcnt, 0, 512 * 4, stream);
    k_bin<<<nbin, 512, 0, stream>>>(ei, E, gcnt, binned, B);
    k_bucket_csr<<<B, 1024, 0, stream>>>(binned, gcnt, x, iptr2, dinv, p1, csr, n);
    k_agg2_l1<<<nblocks, 256, 0, stream>>>(p1, iptr2, csr, dinv, W1, b1, aggx, p2, n);
    k_agg30<<<(n + 31) / 32, 256, 0, stream>>>((const uint2*)p2, iptr2, csr, dinv,
                                               (uint2*)aggh, n);
    k_layer2<<<nblocks, 256, 0, stream>>>(aggh, aggx, x, W2, W3, b2, dinv, p3, n);
    k_agg1<<<nblocks, 256, 0, stream>>>(p3, iptr2, csr, dinv, b3, out, n);
}

// Round 15
// 248.305 us; speedup vs baseline: 1.0788x; 1.0788x over previous
//
#include <hip/hip_runtime.h>
#include <stdint.h>

// 3-layer GCN, gather-only aggregation off a per-node CSR.
// R14 = R12 verbatim (best known: 243.7us). R13's additions both regressed:
// NT loads on csr defeated its L2 reuse (FETCH +15MB), and the x4 remainder
// pushed k_agg30 to 40 VGPR (occupancy 70->53%). Locked-in configuration:
//  k_bin: CHUNK 6400, fused hist+LDS-sort+linear copy-out, shuffle scan.
//  k_bucket_csr: 1024 thr, shuffle scan, direct scatter to owned region.
//  k_agg2_l1 / k_agg30 / k_layer2 / k_agg1: x8-unrolled cached gathers,
//  fp64 accumulators (order-independent), bf16 64B rows for dim-30.
// Packed edge = (src<<9)|(dst&511), src < 2^18.

#define CAP 9216    // bucket region capacity; mean 8184, sigma 90 -> +11 sigma
#define CHUNK 6400  // edges per k_bin block

__device__ __forceinline__ unsigned short f2bf(float f) {  // RNE, no NaN inputs
    unsigned u = __float_as_uint(f);
    unsigned r = ((u >> 16) & 1u) + 0x7FFFu;
    return (unsigned short)((u + r) >> 16);
}
__device__ __forceinline__ float bf2f(unsigned short h) {
    return __uint_as_float((unsigned)h << 16);
}

// Per-block int64-vs-int32 detect: int64 edge values < 2^18 => all high
// words zero; int32 data at those offsets is src values, ~surely nonzero.
__device__ __forceinline__ int detect64(const unsigned* ei, int* s_nz, int t) {
    unsigned v = ei[2 * (t & 255) + 1];
    if (v != 0) atomicAdd(s_nz, 1);
    __syncthreads();
    return (*s_nz == 0);
}

// Fused binning with local counting sort and coalesced copy-out. 512 thr.
__global__ __launch_bounds__(512) void k_bin(const void* ei, long long E,
                                             int* gcnt, unsigned* binned, int B) {
    __shared__ int cursor[512];
    __shared__ int delta[512];
    __shared__ int wsum[8];
    __shared__ int s_total;
    __shared__ unsigned sv[CHUNK];
    __shared__ unsigned short sb[CHUNK];
    __shared__ int s_nz;
    int t = threadIdx.x, blk = blockIdx.x;
    if (t == 0) s_nz = 0;
    cursor[t] = 0;
    __syncthreads();
    int f = detect64((const unsigned*)ei, &s_nz, t);
    long long s = (long long)blk * CHUNK, e = min(E, s + CHUNK);
    if (f) {
        const long long* p = (const long long*)ei;
        for (long long i = s + t; i < e; i += 512)
            atomicAdd(&cursor[((int)p[E + i]) >> 9], 1);
    } else {
        const int* p = (const int*)ei;
        for (long long i = s + t; i < e; i += 512)
            atomicAdd(&cursor[p[E + i] >> 9], 1);
    }
    __syncthreads();
    // exclusive scan over 512 counts: wave shuffle scan + cross-wave offsets
    int c = cursor[t];
    int lane = t & 63, wid = t >> 6;
    int inc = c;
#pragma unroll
    for (int off = 1; off < 64; off <<= 1) {
        int up = __shfl_up(inc, off, 64);
        if (lane >= off) inc += up;
    }
    if (lane == 63) wsum[wid] = inc;
    __syncthreads();
    int base = 0;
    for (int k = 0; k < wid; k++) base += wsum[k];
    int ex = base + inc - c;
    if (t == 511) s_total = ex + c;
    int claim = c ? atomicAdd(&gcnt[t], c) : 0;
    delta[t] = t * CAP + claim - ex;
    cursor[t] = ex;
    __syncthreads();
    // scatter into LDS (sorted by bucket), remember bucket id
    if (f) {
        const long long* p = (const long long*)ei;
        for (long long i = s + t; i < e; i += 512) {
            int sval = (int)p[i], dv = (int)p[E + i];
            int b = dv >> 9;
            int pos = atomicAdd(&cursor[b], 1);
            sv[pos] = ((unsigned)sval << 9) | (unsigned)(dv & 511);
            sb[pos] = (unsigned short)b;
        }
    } else {
        const int* p = (const int*)ei;
        for (long long i = s + t; i < e; i += 512) {
            int sval = p[i], dv = p[E + i];
            int b = dv >> 9;
            int pos = atomicAdd(&cursor[b], 1);
            sv[pos] = ((unsigned)sval << 9) | (unsigned)(dv & 511);
            sb[pos] = (unsigned short)b;
        }
    }
    __syncthreads();
    // linear copy-out (consecutive threads -> consecutive addresses)
    int total = s_total;
    for (int i = t; i < total; i += 512)
        binned[delta[sb[i]] + i] = sv[i];
}

// Per-bucket counting sort by local node, scattering csr DIRECTLY to the
// block-owned global region. 1024 threads; shuffle scan over 512 counters.
// Also iptr2, dinv, p1 = x*dinv.
__global__ __launch_bounds__(1024) void k_bucket_csr(
        const unsigned* binned, const int* gcnt, const float* x, int2* iptr2,
        float* dinv, float2* p1, int* csr, int n) {
    __shared__ int cur[512];
    __shared__ int wsum[16];
    int t = threadIdx.x, b = blockIdx.x;
    if (t < 512) cur[t] = 0;
    __syncthreads();
    int cnt = gcnt[b];
    const unsigned* bp = binned + (size_t)b * CAP;
    for (int i = t; i < cnt; i += 1024)
        atomicAdd(&cur[bp[i] & 511u], 1);
    __syncthreads();
    int c = (t < 512) ? cur[t] : 0;
    int lane = t & 63, wid = t >> 6;
    int inc = c;
#pragma unroll
    for (int off = 1; off < 64; off <<= 1) {
        int up = __shfl_up(inc, off, 64);
        if (lane >= off) inc += up;
    }
    if (lane == 63) wsum[wid] = inc;
    __syncthreads();
    int base = 0;
    for (int k = 0; k < wid; k++) base += wsum[k];
    int ex = base + inc - c;
    int gbase = b * CAP;
    if (t < 512) {
        cur[t] = gbase + ex;  // global cursor
        int node = b * 512 + t;
        if (node < n) {
            iptr2[node] = make_int2(gbase + ex, gbase + ex + c);
            float dg = (float)(c + 1);  // +1 self loop
            float r = rsqrtf(dg);
            r = r * (1.5f - 0.5f * dg * r * r);  // Newton refine
            dinv[node] = r;
            p1[node] = make_float2(x[2 * node] * r, x[2 * node + 1] * r);
        }
    }
    __syncthreads();
    for (int i = t; i < cnt; i += 1024) {
        unsigned p = bp[i];
        int pos = atomicAdd(&cur[p & 511u], 1);
        csr[pos] = (int)(p >> 9);
    }
}

// Fused: aggx = A_hat x (dim2, x8 unroll, fp64 acc);
// p2 = bf16(relu(aggx@W1+b1)*dinv), 64B rows (32 ushorts, 2 zero pads).
__global__ void k_agg2_l1(const float2* p1, const int2* iptr2, const int* csr,
                          const float* dinv, const float* W1, const float* b1,
                          float2* aggx, unsigned short* p2, int n) {
    int v = blockIdx.x * 256 + threadIdx.x;
    if (v >= n) return;
    float2 a0 = p1[v];
    double dax = a0.x, day = a0.y;
    int2 se = iptr2[v];
    int s = se.x, e = se.y;
    int i = s;
    for (; i + 7 < e; i += 8) {
        int u0 = csr[i], u1 = csr[i + 1], u2 = csr[i + 2], u3 = csr[i + 3];
        int u4 = csr[i + 4], u5 = csr[i + 5], u6 = csr[i + 6], u7 = csr[i + 7];
        float2 q0 = p1[u0], q1 = p1[u1], q2 = p1[u2], q3 = p1[u3];
        float2 q4 = p1[u4], q5 = p1[u5], q6 = p1[u6], q7 = p1[u7];
        dax += ((double)q0.x + q1.x) + ((double)q2.x + q3.x) +
               ((double)q4.x + q5.x) + ((double)q6.x + q7.x);
        day += ((double)q0.y + q1.y) + ((double)q2.y + q3.y) +
               ((double)q4.y + q5.y) + ((double)q6.y + q7.y);
    }
    for (; i < e; i++) {
        float2 q = p1[csr[i]];
        dax += (double)q.x; day += (double)q.y;
    }
    float r = dinv[v];
    float ax = (float)(dax * (double)r), ay = (float)(day * (double)r);
    aggx[v] = make_float2(ax, ay);
    __align__(16) unsigned short ob[32];
#pragma unroll
    for (int j = 0; j < 30; j++)
        ob[j] = f2bf(fmaxf(fmaf(ax, W1[j], fmaf(ay, W1[30 + j], b1[j])), 0.f) * r);
    ob[30] = 0; ob[31] = 0;
    uint4* d4 = (uint4*)(p2 + (size_t)v * 32);
    const uint4* s4 = (const uint4*)ob;
#pragma unroll
    for (int k = 0; k < 4; k++) d4[k] = s4[k];
}

// Dim-30 aggregation: 8-lane group per node, each lane a uint2 (4 bf16,
// 64B/row/group), x8-unrolled independent gathers, fp64 accumulators.
__global__ void k_agg30(const uint2* p2u, const int2* iptr2,
                        const int* csr, const float* dinv,
                        uint2* agghu, int n) {
    int t = threadIdx.x;
    int g = blockIdx.x * 32 + (t >> 3);
    int l = t & 7;
    if (g >= n) return;
    uint2 w = p2u[(size_t)g * 8 + l];  // self loop (pads zero)
    double a0 = (double)bf2f((unsigned short)(w.x & 0xFFFFu));
    double a1 = (double)bf2f((unsigned short)(w.x >> 16));
    double a2 = (double)bf2f((unsigned short)(w.y & 0xFFFFu));
    double a3 = (double)bf2f((unsigned short)(w.y >> 16));
    int2 se = iptr2[g];
    int s = se.x, e = se.y;
    int i = s;
    for (; i + 7 < e; i += 8) {
        int u0 = csr[i], u1 = csr[i + 1], u2 = csr[i + 2], u3 = csr[i + 3];
        int u4 = csr[i + 4], u5 = csr[i + 5], u6 = csr[i + 6], u7 = csr[i + 7];
        uint2 w0 = p2u[(size_t)u0 * 8 + l];
        uint2 w1 = p2u[(size_t)u1 * 8 + l];
        uint2 w2 = p2u[(size_t)u2 * 8 + l];
        uint2 w3 = p2u[(size_t)u3 * 8 + l];
        uint2 w4 = p2u[(size_t)u4 * 8 + l];
        uint2 w5 = p2u[(size_t)u5 * 8 + l];
        uint2 w6 = p2u[(size_t)u6 * 8 + l];
        uint2 w7 = p2u[(size_t)u7 * 8 + l];
        a0 += ((double)bf2f((unsigned short)(w0.x & 0xFFFFu)) + bf2f((unsigned short)(w1.x & 0xFFFFu))) +
              ((double)bf2f((unsigned short)(w2.x & 0xFFFFu)) + bf2f((unsigned short)(w3.x & 0xFFFFu))) +
              ((double)bf2f((unsigned short)(w4.x & 0xFFFFu)) + bf2f((unsigned short)(w5.x & 0xFFFFu))) +
              ((double)bf2f((unsigned short)(w6.x & 0xFFFFu)) + bf2f((unsigned short)(w7.x & 0xFFFFu)));
        a1 += ((double)bf2f((unsigned short)(w0.x >> 16)) + bf2f((unsigned short)(w1.x >> 16))) +
              ((double)bf2f((unsigned short)(w2.x >> 16)) + bf2f((unsigned short)(w3.x >> 16))) +
              ((double)bf2f((unsigned short)(w4.x >> 16)) + bf2f((unsigned short)(w5.x >> 16))) +
              ((double)bf2f((unsigned short)(w6.x >> 16)) + bf2f((unsigned short)(w7.x >> 16)));
        a2 += ((double)bf2f((unsigned short)(w0.y & 0xFFFFu)) + bf2f((unsigned short)(w1.y & 0xFFFFu))) +
              ((double)bf2f((unsigned short)(w2.y & 0xFFFFu)) + bf2f((unsigned short)(w3.y & 0xFFFFu))) +
              ((double)bf2f((unsigned short)(w4.y & 0xFFFFu)) + bf2f((unsigned short)(w5.y & 0xFFFFu))) +
              ((double)bf2f((unsigned short)(w6.y & 0xFFFFu)) + bf2f((unsigned short)(w7.y & 0xFFFFu)));
        a3 += ((double)bf2f((unsigned short)(w0.y >> 16)) + bf2f((unsigned short)(w1.y >> 16))) +
              ((double)bf2f((unsigned short)(w2.y >> 16)) + bf2f((unsigned short)(w3.y >> 16))) +
              ((double)bf2f((unsigned short)(w4.y >> 16)) + bf2f((unsigned short)(w5.y >> 16))) +
              ((double)bf2f((unsigned short)(w6.y >> 16)) + bf2f((unsigned short)(w7.y >> 16)));
    }
    for (; i < e; i++) {
        uint2 wv = p2u[(size_t)csr[i] * 8 + l];
        a0 += (double)bf2f((unsigned short)(wv.x & 0xFFFFu));
        a1 += (double)bf2f((unsigned short)(wv.x >> 16));
        a2 += (double)bf2f((unsigned short)(wv.y & 0xFFFFu));
        a3 += (double)bf2f((unsigned short)(wv.y >> 16));
    }
    double r = (double)dinv[g];
    uint2 o;
    o.x = (unsigned)f2bf((float)(a0 * r)) | ((unsigned)f2bf((float)(a1 * r)) << 16);
    o.y = (unsigned)f2bf((float)(a2 * r)) | ((unsigned)f2bf((float)(a3 * r)) << 16);
    agghu[(size_t)g * 8 + l] = o;  // pads (cols 30,31) are zero-sums -> stay 0
}

// h2 = relu((Ah1)W2[:30] + (Ax)W2[30:] + b2); p3 = ([h2,x]@W3) * dinv.
// Block stages its 256 bf16 aggh rows through LDS (stride-17 uints).
__global__ void k_layer2(const unsigned short* aggh, const float2* aggx,
                         const float* x, const float* W2, const float* W3,
                         const float* b2, const float* dinv, float* p3, int n) {
    __shared__ float W2s[32 * 30];
    __shared__ float W3s[32];
    __shared__ float b2s[30];
    __shared__ unsigned hsh[256 * 17];
    int t = threadIdx.x;
    for (int i = t; i < 960; i += 256) W2s[i] = W2[i];
    if (t < 32) W3s[t] = W3[t];
    if (t < 30) b2s[t] = b2[t];
    const unsigned* ag = (const unsigned*)aggh + (size_t)blockIdx.x * 256 * 16;
    int rows = min(256, n - blockIdx.x * 256);
    for (int i = t; i < rows * 16; i += 256) {
        int rr = i >> 4, cc = i & 15;
        hsh[rr * 17 + cc] = ag[i];
    }
    __syncthreads();
    int v = blockIdx.x * 256 + t;
    if (v >= n) return;
    float2 a = aggx[v];
    float acc[30];
#pragma unroll
    for (int j = 0; j < 30; j++)
        acc[j] = fmaf(a.x, W2s[30 * 30 + j], fmaf(a.y, W2s[31 * 30 + j], b2s[j]));
#pragma unroll
    for (int kk = 0; kk < 15; kk++) {  // 30 values = 15 uint pairs
        unsigned pr = hsh[t * 17 + kk];
        float h0 = bf2f((unsigned short)(pr & 0xFFFFu));
        float h1v = bf2f((unsigned short)(pr >> 16));
#pragma unroll
        for (int j = 0; j < 30; j++)
            acc[j] = fmaf(h0, W2s[(2 * kk) * 30 + j], acc[j]);
#pragma unroll
        for (int j = 0; j < 30; j++)
            acc[j] = fmaf(h1v, W2s[(2 * kk + 1) * 30 + j], acc[j]);
    }
    float s3 = 0.f;
#pragma unroll
    for (int j = 0; j < 30; j++) s3 = fmaf(fmaxf(acc[j], 0.f), W3s[j], s3);
    s3 = fmaf(x[2 * v], W3s[30], s3);
    s3 = fmaf(x[2 * v + 1], W3s[31], s3);
    p3[v] = s3 * dinv[v];
}

// out_v = dinv_v * (p3_v + sum p3_u) + b3   (dim 1, x8 unroll, fp64 acc)
__global__ void k_agg1(const float* p3, const int2* iptr2, const int* csr,
                       const float* dinv, const float* b3, float* out, int n) {
    int v = blockIdx.x * 256 + threadIdx.x;
    if (v >= n) return;
    double acc = (double)p3[v];
    int2 se = iptr2[v];
    int s = se.x, e = se.y;
    int i = s;
    for (; i + 7 < e; i += 8) {
        int u0 = csr[i], u1 = csr[i + 1], u2 = csr[i + 2], u3 = csr[i + 3];
        int u4 = csr[i + 4], u5 = csr[i + 5], u6 = csr[i + 6], u7 = csr[i + 7];
        float f0 = p3[u0], f1 = p3[u1], f2 = p3[u2], f3 = p3[u3];
        float f4 = p3[u4], f5 = p3[u5], f6 = p3[u6], f7 = p3[u7];
        acc += ((double)f0 + f1) + ((double)f2 + f3) +
               ((double)f4 + f5) + ((double)f6 + f7);
    }
    for (; i < e; i++) acc += (double)p3[csr[i]];
    out[v] = (float)(acc * (double)dinv[v] + (double)b3[0]);
}

extern "C" void kernel_launch(void* const* d_in, const int* in_sizes, int n_in,
                              void* d_out, int out_size, void* d_ws, size_t ws_size,
                              hipStream_t stream) {
    const float* x  = (const float*)d_in[0];
    const void*  ei = d_in[1];
    const float* W1 = (const float*)d_in[2];
    const float* b1 = (const float*)d_in[3];
    const float* W2 = (const float*)d_in[4];
    const float* b2 = (const float*)d_in[5];
    const float* W3 = (const float*)d_in[6];
    const float* b3 = (const float*)d_in[7];
    float* out = (float*)d_out;
    const int n = in_sizes[0] / 2;
    const long long E = in_sizes[1] / 2;
    const int B = (n + 511) / 512;  // dst buckets of 512 nodes (<=512 buckets)

    char* w = (char*)d_ws;
    auto alloc = [&](size_t b) { void* p = (void*)w; w += (b + 255) & ~(size_t)255; return p; };
    int*            gcnt   = (int*)alloc(512 * 4);
    unsigned*       binned = (unsigned*)alloc((size_t)B * CAP * 4);
    int*            csr    = (int*)alloc((size_t)B * CAP * 4);
    int2*           iptr2  = (int2*)alloc((size_t)n * 8);
    float*          dinv   = (float*)alloc((size_t)n * 4);
    float2*         p1     = (float2*)alloc((size_t)n * 8);
    float2*         aggx   = (float2*)alloc((size_t)n * 8);
    unsigned short* p2     = (unsigned short*)alloc((size_t)n * 32 * 2);
    unsigned short* aggh   = (unsigned short*)alloc((size_t)n * 32 * 2);
    float*          p3     = (float*)alloc((size_t)n * 4);

    int nblocks = (n + 255) / 256;
    int nbin = (int)((E + CHUNK - 1) / CHUNK);

    hipMemsetAsync(gcnt, 0, 512 * 4, stream);
    k_bin<<<nbin, 512, 0, stream>>>(ei, E, gcnt, binned, B);
    k_bucket_csr<<<B, 1024, 0, stream>>>(binned, gcnt, x, iptr2, dinv, p1, csr, n);
    k_agg2_l1<<<nblocks, 256, 0, stream>>>(p1, iptr2, csr, dinv, W1, b1, aggx, p2, n);
    k_agg30<<<(n + 31) / 32, 256, 0, stream>>>((const uint2*)p2, iptr2, csr, dinv,
                                               (uint2*)aggh, n);
    k_layer2<<<nblocks, 256, 0, stream>>>(aggh, aggx, x, W2, W3, b2, dinv, p3, n);
    k_agg1<<<nblocks, 256, 0, stream>>>(p3, iptr2, csr, dinv, b3, out, n);
}

// Round 16
// 241.558 us; speedup vs baseline: 1.1089x; 1.0279x over previous
//
#include <hip/hip_runtime.h>
#include <stdint.h>

// 3-layer GCN, gather-only aggregation off a per-node CSR.
// R15 = R12/R14 locked configuration + ONE isolated change: k_bin reads the
// edge list as pairs (int2 / longlong2 vector loads; dst halves are 8/16B
// aligned because E and chunk starts are even) -- halves VMEM instructions
// and loop iterations of an instruction-bound kernel. Everything else is
// byte-identical to the proven best (243.7us; run-to-run band +-2%).
//  k_bin: CHUNK 6400, fused hist+LDS-sort+linear copy-out, shuffle scan.
//  k_bucket_csr: 1024 thr, shuffle scan, direct scatter to owned region.
//  k_agg2_l1 / k_agg30 / k_layer2 / k_agg1: x8-unrolled cached gathers,
//  fp64 accumulators (order-independent), bf16 64B rows for dim-30.
// Packed edge = (src<<9)|(dst&511), src < 2^18.

#define CAP 9216    // bucket region capacity; mean 8184, sigma 90 -> +11 sigma
#define CHUNK 6400  // edges per k_bin block

__device__ __forceinline__ unsigned short f2bf(float f) {  // RNE, no NaN inputs
    unsigned u = __float_as_uint(f);
    unsigned r = ((u >> 16) & 1u) + 0x7FFFu;
    return (unsigned short)((u + r) >> 16);
}
__device__ __forceinline__ float bf2f(unsigned short h) {
    return __uint_as_float((unsigned)h << 16);
}

// Per-block int64-vs-int32 detect: int64 edge values < 2^18 => all high
// words zero; int32 data at those offsets is src values, ~surely nonzero.
__device__ __forceinline__ int detect64(const unsigned* ei, int* s_nz, int t) {
    unsigned v = ei[2 * (t & 255) + 1];
    if (v != 0) atomicAdd(s_nz, 1);
    __syncthreads();
    return (*s_nz == 0);
}

// Fused binning with local counting sort and coalesced copy-out. 512 thr.
// Edge list consumed in PAIRS via vector loads.
__global__ __launch_bounds__(512) void k_bin(const void* ei, long long E,
                                             int* gcnt, unsigned* binned, int B) {
    __shared__ int cursor[512];
    __shared__ int delta[512];
    __shared__ int wsum[8];
    __shared__ int s_total;
    __shared__ unsigned sv[CHUNK];
    __shared__ unsigned short sb[CHUNK];
    __shared__ int s_nz;
    int t = threadIdx.x, blk = blockIdx.x;
    if (t == 0) s_nz = 0;
    cursor[t] = 0;
    __syncthreads();
    int f = detect64((const unsigned*)ei, &s_nz, t);
    long long s = (long long)blk * CHUNK, e = min(E, s + CHUNK);
    // ---- histogram (pairs) ----
    if (f) {
        const long long* p = (const long long*)ei;
        long long i = s + 2 * t;
        for (; i + 1 < e; i += 1024) {
            longlong2 d = *(const longlong2*)(p + E + i);
            atomicAdd(&cursor[((int)d.x) >> 9], 1);
            atomicAdd(&cursor[((int)d.y) >> 9], 1);
        }
        if (i < e) atomicAdd(&cursor[((int)p[E + i]) >> 9], 1);
    } else {
        const int* p = (const int*)ei;
        long long i = s + 2 * t;
        for (; i + 1 < e; i += 1024) {
            int2 d = *(const int2*)(p + E + i);
            atomicAdd(&cursor[d.x >> 9], 1);
            atomicAdd(&cursor[d.y >> 9], 1);
        }
        if (i < e) atomicAdd(&cursor[p[E + i] >> 9], 1);
    }
    __syncthreads();
    // exclusive scan over 512 counts: wave shuffle scan + cross-wave offsets
    int c = cursor[t];
    int lane = t & 63, wid = t >> 6;
    int inc = c;
#pragma unroll
    for (int off = 1; off < 64; off <<= 1) {
        int up = __shfl_up(inc, off, 64);
        if (lane >= off) inc += up;
    }
    if (lane == 63) wsum[wid] = inc;
    __syncthreads();
    int base = 0;
    for (int k = 0; k < wid; k++) base += wsum[k];
    int ex = base + inc - c;
    if (t == 511) s_total = ex + c;
    int claim = c ? atomicAdd(&gcnt[t], c) : 0;
    delta[t] = t * CAP + claim - ex;
    cursor[t] = ex;
    __syncthreads();
    // ---- scatter into LDS (pairs), remember bucket id ----
    if (f) {
        const long long* p = (const long long*)ei;
        long long i = s + 2 * t;
        for (; i + 1 < e; i += 1024) {
            longlong2 sp = *(const longlong2*)(p + i);
            longlong2 dp = *(const longlong2*)(p + E + i);
            int b0 = ((int)dp.x) >> 9, b1 = ((int)dp.y) >> 9;
            int p0 = atomicAdd(&cursor[b0], 1);
            sv[p0] = ((unsigned)(int)sp.x << 9) | (unsigned)((int)dp.x & 511);
            sb[p0] = (unsigned short)b0;
            int p1v = atomicAdd(&cursor[b1], 1);
            sv[p1v] = ((unsigned)(int)sp.y << 9) | (unsigned)((int)dp.y & 511);
            sb[p1v] = (unsigned short)b1;
        }
        if (i < e) {
            int sval = (int)p[i], dv = (int)p[E + i];
            int b = dv >> 9;
            int pos = atomicAdd(&cursor[b], 1);
            sv[pos] = ((unsigned)sval << 9) | (unsigned)(dv & 511);
            sb[pos] = (unsigned short)b;
        }
    } else {
        const int* p = (const int*)ei;
        long long i = s + 2 * t;
        for (; i + 1 < e; i += 1024) {
            int2 sp = *(const int2*)(p + i);
            int2 dp = *(const int2*)(p + E + i);
            int b0 = dp.x >> 9, b1 = dp.y >> 9;
            int p0 = atomicAdd(&cursor[b0], 1);
            sv[p0] = ((unsigned)sp.x << 9) | (unsigned)(dp.x & 511);
            sb[p0] = (unsigned short)b0;
            int p1v = atomicAdd(&cursor[b1], 1);
            sv[p1v] = ((unsigned)sp.y << 9) | (unsigned)(dp.y & 511);
            sb[p1v] = (unsigned short)b1;
        }
        if (i < e) {
            int sval = p[i], dv = p[E + i];
            int b = dv >> 9;
            int pos = atomicAdd(&cursor[b], 1);
            sv[pos] = ((unsigned)sval << 9) | (unsigned)(dv & 511);
            sb[pos] = (unsigned short)b;
        }
    }
    __syncthreads();
    // linear copy-out (consecutive threads -> consecutive addresses)
    int total = s_total;
    for (int i = t; i < total; i += 512)
        binned[delta[sb[i]] + i] = sv[i];
}

// Per-bucket counting sort by local node, scattering csr DIRECTLY to the
// block-owned global region. 1024 threads; shuffle scan over 512 counters.
// Also iptr2, dinv, p1 = x*dinv.
__global__ __launch_bounds__(1024) void k_bucket_csr(
        const unsigned* binned, const int* gcnt, const float* x, int2* iptr2,
        float* dinv, float2* p1, int* csr, int n) {
    __shared__ int cur[512];
    __shared__ int wsum[16];
    int t = threadIdx.x, b = blockIdx.x;
    if (t < 512) cur[t] = 0;
    __syncthreads();
    int cnt = gcnt[b];
    const unsigned* bp = binned + (size_t)b * CAP;
    for (int i = t; i < cnt; i += 1024)
        atomicAdd(&cur[bp[i] & 511u], 1);
    __syncthreads();
    int c = (t < 512) ? cur[t] : 0;
    int lane = t & 63, wid = t >> 6;
    int inc = c;
#pragma unroll
    for (int off = 1; off < 64; off <<= 1) {
        int up = __shfl_up(inc, off, 64);
        if (lane >= off) inc += up;
    }
    if (lane == 63) wsum[wid] = inc;
    __syncthreads();
    int base = 0;
    for (int k = 0; k < wid; k++) base += wsum[k];
    int ex = base + inc - c;
    int gbase = b * CAP;
    if (t < 512) {
        cur[t] = gbase + ex;  // global cursor
        int node = b * 512 + t;
        if (node < n) {
            iptr2[node] = make_int2(gbase + ex, gbase + ex + c);
            float dg = (float)(c + 1);  // +1 self loop
            float r = rsqrtf(dg);
            r = r * (1.5f - 0.5f * dg * r * r);  // Newton refine
            dinv[node] = r;
            p1[node] = make_float2(x[2 * node] * r, x[2 * node + 1] * r);
        }
    }
    __syncthreads();
    for (int i = t; i < cnt; i += 1024) {
        unsigned p = bp[i];
        int pos = atomicAdd(&cur[p & 511u], 1);
        csr[pos] = (int)(p >> 9);
    }
}

// Fused: aggx = A_hat x (dim2, x8 unroll, fp64 acc);
// p2 = bf16(relu(aggx@W1+b1)*dinv), 64B rows (32 ushorts, 2 zero pads).
__global__ void k_agg2_l1(const float2* p1, const int2* iptr2, const int* csr,
                          const float* dinv, const float* W1, const float* b1,
                          float2* aggx, unsigned short* p2, int n) {
    int v = blockIdx.x * 256 + threadIdx.x;
    if (v >= n) return;
    float2 a0 = p1[v];
    double dax = a0.x, day = a0.y;
    int2 se = iptr2[v];
    int s = se.x, e = se.y;
    int i = s;
    for (; i + 7 < e; i += 8) {
        int u0 = csr[i], u1 = csr[i + 1], u2 = csr[i + 2], u3 = csr[i + 3];
        int u4 = csr[i + 4], u5 = csr[i + 5], u6 = csr[i + 6], u7 = csr[i + 7];
        float2 q0 = p1[u0], q1 = p1[u1], q2 = p1[u2], q3 = p1[u3];
        float2 q4 = p1[u4], q5 = p1[u5], q6 = p1[u6], q7 = p1[u7];
        dax += ((double)q0.x + q1.x) + ((double)q2.x + q3.x) +
               ((double)q4.x + q5.x) + ((double)q6.x + q7.x);
        day += ((double)q0.y + q1.y) + ((double)q2.y + q3.y) +
               ((double)q4.y + q5.y) + ((double)q6.y + q7.y);
    }
    for (; i < e; i++) {
        float2 q = p1[csr[i]];
        dax += (double)q.x; day += (double)q.y;
    }
    float r = dinv[v];
    float ax = (float)(dax * (double)r), ay = (float)(day * (double)r);
    aggx[v] = make_float2(ax, ay);
    __align__(16) unsigned short ob[32];
#pragma unroll
    for (int j = 0; j < 30; j++)
        ob[j] = f2bf(fmaxf(fmaf(ax, W1[j], fmaf(ay, W1[30 + j], b1[j])), 0.f) * r);
    ob[30] = 0; ob[31] = 0;
    uint4* d4 = (uint4*)(p2 + (size_t)v * 32);
    const uint4* s4 = (const uint4*)ob;
#pragma unroll
    for (int k = 0; k < 4; k++) d4[k] = s4[k];
}

// Dim-30 aggregation: 8-lane group per node, each lane a uint2 (4 bf16,
// 64B/row/group), x8-unrolled independent gathers, fp64 accumulators.
__global__ void k_agg30(const uint2* p2u, const int2* iptr2,
                        const int* csr, const float* dinv,
                        uint2* agghu, int n) {
    int t = threadIdx.x;
    int g = blockIdx.x * 32 + (t >> 3);
    int l = t & 7;
    if (g >= n) return;
    uint2 w = p2u[(size_t)g * 8 + l];  // self loop (pads zero)
    double a0 = (double)bf2f((unsigned short)(w.x & 0xFFFFu));
    double a1 = (double)bf2f((unsigned short)(w.x >> 16));
    double a2 = (double)bf2f((unsigned short)(w.y & 0xFFFFu));
    double a3 = (double)bf2f((unsigned short)(w.y >> 16));
    int2 se = iptr2[g];
    int s = se.x, e = se.y;
    int i = s;
    for (; i + 7 < e; i += 8) {
        int u0 = csr[i], u1 = csr[i + 1], u2 = csr[i + 2], u3 = csr[i + 3];
        int u4 = csr[i + 4], u5 = csr[i + 5], u6 = csr[i + 6], u7 = csr[i + 7];
        uint2 w0 = p2u[(size_t)u0 * 8 + l];
        uint2 w1 = p2u[(size_t)u1 * 8 + l];
        uint2 w2 = p2u[(size_t)u2 * 8 + l];
        uint2 w3 = p2u[(size_t)u3 * 8 + l];
        uint2 w4 = p2u[(size_t)u4 * 8 + l];
        uint2 w5 = p2u[(size_t)u5 * 8 + l];
        uint2 w6 = p2u[(size_t)u6 * 8 + l];
        uint2 w7 = p2u[(size_t)u7 * 8 + l];
        a0 += ((double)bf2f((unsigned short)(w0.x & 0xFFFFu)) + bf2f((unsigned short)(w1.x & 0xFFFFu))) +
              ((double)bf2f((unsigned short)(w2.x & 0xFFFFu)) + bf2f((unsigned short)(w3.x & 0xFFFFu))) +
              ((double)bf2f((unsigned short)(w4.x & 0xFFFFu)) + bf2f((unsigned short)(w5.x & 0xFFFFu))) +
              ((double)bf2f((unsigned short)(w6.x & 0xFFFFu)) + bf2f((unsigned short)(w7.x & 0xFFFFu)));
        a1 += ((double)bf2f((unsigned short)(w0.x >> 16)) + bf2f((unsigned short)(w1.x >> 16))) +
              ((double)bf2f((unsigned short)(w2.x >> 16)) + bf2f((unsigned short)(w3.x >> 16))) +
              ((double)bf2f((unsigned short)(w4.x >> 16)) + bf2f((unsigned short)(w5.x >> 16))) +
              ((double)bf2f((unsigned short)(w6.x >> 16)) + bf2f((unsigned short)(w7.x >> 16)));
        a2 += ((double)bf2f((unsigned short)(w0.y & 0xFFFFu)) + bf2f((unsigned short)(w1.y & 0xFFFFu))) +
              ((double)bf2f((unsigned short)(w2.y & 0xFFFFu)) + bf2f((unsigned short)(w3.y & 0xFFFFu))) +
              ((double)bf2f((unsigned short)(w4.y & 0xFFFFu)) + bf2f((unsigned short)(w5.y & 0xFFFFu))) +
              ((double)bf2f((unsigned short)(w6.y & 0xFFFFu)) + bf2f((unsigned short)(w7.y & 0xFFFFu)));
        a3 += ((double)bf2f((unsigned short)(w0.y >> 16)) + bf2f((unsigned short)(w1.y >> 16))) +
              ((double)bf2f((unsigned short)(w2.y >> 16)) + bf2f((unsigned short)(w3.y >> 16))) +
              ((double)bf2f((unsigned short)(w4.y >> 16)) + bf2f((unsigned short)(w5.y >> 16))) +
              ((double)bf2f((unsigned short)(w6.y >> 16)) + bf2f((unsigned short)(w7.y >> 16)));
    }
    for (; i < e; i++) {
        uint2 wv = p2u[(size_t)csr[i] * 8 + l];
        a0 += (double)bf2f((unsigned short)(wv.x & 0xFFFFu));
        a1 += (double)bf2f((unsigned short)(wv.x >> 16));
        a2 += (double)bf2f((unsigned short)(wv.y & 0xFFFFu));
        a3 += (double)bf2f((unsigned short)(wv.y >> 16));
    }
    double r = (double)dinv[g];
    uint2 o;
    o.x = (unsigned)f2bf((float)(a0 * r)) | ((unsigned)f2bf((float)(a1 * r)) << 16);
    o.y = (unsigned)f2bf((float)(a2 * r)) | ((unsigned)f2bf((float)(a3 * r)) << 16);
    agghu[(size_t)g * 8 + l] = o;  // pads (cols 30,31) are zero-sums -> stay 0
}

// h2 = relu((Ah1)W2[:30] + (Ax)W2[30:] + b2); p3 = ([h2,x]@W3) * dinv.
// Block stages its 256 bf16 aggh rows through LDS (stride-17 uints).
__global__ void k_layer2(const unsigned short* aggh, const float2* aggx,
                         const float* x, const float* W2, const float* W3,
                         const float* b2, const float* dinv, float* p3, int n) {
    __shared__ float W2s[32 * 30];
    __shared__ float W3s[32];
    __shared__ float b2s[30];
    __shared__ unsigned hsh[256 * 17];
    int t = threadIdx.x;
    for (int i = t; i < 960; i += 256) W2s[i] = W2[i];
    if (t < 32) W3s[t] = W3[t];
    if (t < 30) b2s[t] = b2[t];
    const unsigned* ag = (const unsigned*)aggh + (size_t)blockIdx.x * 256 * 16;
    int rows = min(256, n - blockIdx.x * 256);
    for (int i = t; i < rows * 16; i += 256) {
        int rr = i >> 4, cc = i & 15;
        hsh[rr * 17 + cc] = ag[i];
    }
    __syncthreads();
    int v = blockIdx.x * 256 + t;
    if (v >= n) return;
    float2 a = aggx[v];
    float acc[30];
#pragma unroll
    for (int j = 0; j < 30; j++)
        acc[j] = fmaf(a.x, W2s[30 * 30 + j], fmaf(a.y, W2s[31 * 30 + j], b2s[j]));
#pragma unroll
    for (int kk = 0; kk < 15; kk++) {  // 30 values = 15 uint pairs
        unsigned pr = hsh[t * 17 + kk];
        float h0 = bf2f((unsigned short)(pr & 0xFFFFu));
        float h1v = bf2f((unsigned short)(pr >> 16));
#pragma unroll
        for (int j = 0; j < 30; j++)
            acc[j] = fmaf(h0, W2s[(2 * kk) * 30 + j], acc[j]);
#pragma unroll
        for (int j = 0; j < 30; j++)
            acc[j] = fmaf(h1v, W2s[(2 * kk + 1) * 30 + j], acc[j]);
    }
    float s3 = 0.f;
#pragma unroll
    for (int j = 0; j < 30; j++) s3 = fmaf(fmaxf(acc[j], 0.f), W3s[j], s3);
    s3 = fmaf(x[2 * v], W3s[30], s3);
    s3 = fmaf(x[2 * v + 1], W3s[31], s3);
    p3[v] = s3 * dinv[v];
}

// out_v = dinv_v * (p3_v + sum p3_u) + b3   (dim 1, x8 unroll, fp64 acc)
__global__ void k_agg1(const float* p3, const int2* iptr2, const int* csr,
                       const float* dinv, const float* b3, float* out, int n) {
    int v = blockIdx.x * 256 + threadIdx.x;
    if (v >= n) return;
    double acc = (double)p3[v];
    int2 se = iptr2[v];
    int s = se.x, e = se.y;
    int i = s;
    for (; i + 7 < e; i += 8) {
        int u0 = csr[i], u1 = csr[i + 1], u2 = csr[i + 2], u3 = csr[i + 3];
        int u4 = csr[i + 4], u5 = csr[i + 5], u6 = csr[i + 6], u7 = csr[i + 7];
        float f0 = p3[u0], f1 = p3[u1], f2 = p3[u2], f3 = p3[u3];
        float f4 = p3[u4], f5 = p3[u5], f6 = p3[u6], f7 = p3[u7];
        acc += ((double)f0 + f1) + ((double)f2 + f3) +
               ((double)f4 + f5) + ((double)f6 + f7);
    }
    for (; i < e; i++) acc += (double)p3[csr[i]];
    out[v] = (float)(acc * (double)dinv[v] + (double)b3[0]);
}

extern "C" void kernel_launch(void* const* d_in, const int* in_sizes, int n_in,
                              void* d_out, int out_size, void* d_ws, size_t ws_size,
                              hipStream_t stream) {
    const float* x  = (const float*)d_in[0];
    const void*  ei = d_in[1];
    const float* W1 = (const float*)d_in[2];
    const float* b1 = (const float*)d_in[3];
    const float* W2 = (const float*)d_in[4];
    const float* b2 = (const float*)d_in[5];
    const float* W3 = (const float*)d_in[6];
    const float* b3 = (const float*)d_in[7];
    float* out = (float*)d_out;
    const int n = in_sizes[0] / 2;
    const long long E = in_sizes[1] / 2;
    const int B = (n + 511) / 512;  // dst buckets of 512 nodes (<=512 buckets)

    char* w = (char*)d_ws;
    auto alloc = [&](size_t b) { void* p = (void*)w; w += (b + 255) & ~(size_t)255; return p; };
    int*            gcnt   = (int*)alloc(512 * 4);
    unsigned*       binned = (unsigned*)alloc((size_t)B * CAP * 4);
    int*            csr    = (int*)alloc((size_t)B * CAP * 4);
    int2*           iptr2  = (int2*)alloc((size_t)n * 8);
    float*          dinv   = (float*)alloc((size_t)n * 4);
    float2*         p1     = (float2*)alloc((size_t)n * 8);
    float2*         aggx   = (float2*)alloc((size_t)n * 8);
    unsigned short* p2     = (unsigned short*)alloc((size_t)n * 32 * 2);
    unsigned short* aggh   = (unsigned short*)alloc((size_t)n * 32 * 2);
    float*          p3     = (float*)alloc((size_t)n * 4);

    int nblocks = (n + 255) / 256;
    int nbin = (int)((E + CHUNK - 1) / CHUNK);

    hipMemsetAsync(gcnt, 0, 512 * 4, stream);
    k_bin<<<nbin, 512, 0, stream>>>(ei, E, gcnt, binned, B);
    k_bucket_csr<<<B, 1024, 0, stream>>>(binned, gcnt, x, iptr2, dinv, p1, csr, n);
    k_agg2_l1<<<nblocks, 256, 0, stream>>>(p1, iptr2, csr, dinv, W1, b1, aggx, p2, n);
    k_agg30<<<(n + 31) / 32, 256, 0, stream>>>((const uint2*)p2, iptr2, csr, dinv,
                                               (uint2*)aggh, n);
    k_layer2<<<nblocks, 256, 0, stream>>>(aggh, aggx, x, W2, W3, b2, dinv, p3, n);
    k_agg1<<<nblocks, 256, 0, stream>>>(p3, iptr2, csr, dinv, b3, out, n);
}